// Round 1
// 156.031 us; speedup vs baseline: 1.1424x; 1.1424x over previous
//
#include <hip/hip_runtime.h>
#include <math.h>

#define EPS 1e-5f
#define NBATCH 8
#define NPTS 2048
#define KNB 16
#define BIG 3.2e38f

#define KNN_BLKS (NBATCH * 64)   // 64 chunks of 32 points per batch; uniform grid
#define FUSED_LDS 54400

// ---- workspace layout (in floats) ----
#define WS_PRE 0                            // 16384*24
#define WS_AUX (16384 * 24)                 // 16384*72
#define WS_IDX (WS_AUX + 16384 * 72)        // 16384*16 ints

// Shared by phase 1 and phase 3 — MUST be bitwise identical in both.
__device__ __forceinline__ float dist2f(float mex, float mey, float mez,
                                        float sqn, float4 q) {
  float dot2 = fmaf(mex, q.x, fmaf(mey, q.y, __fmul_rn(mez, q.z)));
  return __fsub_rn(__fadd_rn(sqn, q.w), dot2);
}

// One uniform kernel: every block handles 32 points: pre+aux fold + exact 16-NN.
__global__ __launch_bounds__(512, 4) void fused_kernel(
    const float* __restrict__ x,
    const float* __restrict__ w_pre, const float* __restrict__ b_pre,
    const float* __restrict__ g_pre, const float* __restrict__ be_pre,
    const float* __restrict__ m_pre, const float* __restrict__ v_pre,
    const float* __restrict__ w1, const float* __restrict__ g1,
    const float* __restrict__ be1, const float* __restrict__ m1,
    const float* __restrict__ v1,
    const float* __restrict__ w2, const float* __restrict__ g2,
    const float* __restrict__ be2, const float* __restrict__ m2,
    const float* __restrict__ v2, const float* __restrict__ w3,
    float* __restrict__ pre, float* __restrict__ aux,
    int* __restrict__ knn_out) {
  extern __shared__ char smem[];
  float4* C4   = (float4*)smem;              // [2048] (2x,2y,2z,sq), 32 KB
  float* slist = (float*)(smem + 32768);     // [8 lists][16 vals][32 pts], 16 KB
  // folded-weight area aliases slist (only live before first __syncthreads)
  float* fwp = (float*)(smem + 32768);       // 72
  float* fbp = fwp + 72;                     // 24
  float* fw1 = fbp + 24;                     // 576
  float* fb1 = fw1 + 576;                    // 12
  float* fw2 = fb1 + 12;                     // 720
  float* fb2 = fw2 + 720;                    // 12
  float* sd2   = (float*)(smem + 49152);     // [32][20]
  int*   sidx  = (int*)(smem + 51712);       // [32][20]
  int*   scnt  = (int*)(smem + 54272);       // [32]

  int tid = threadIdx.x;
  int bi = blockIdx.x;
  int b = bi >> 6, chunk = bi & 63;
  const float* xb = x + (size_t)b * 3 * NPTS;

  // ---- Step A: build C4, fold BN into weights, init tie buffers ----
  for (int j = tid; j < NPTS; j += 512) {
    float xx = xb[j], yy = xb[NPTS + j], zz = xb[2 * NPTS + j];
    float sq = __fadd_rn(__fadd_rn(__fmul_rn(xx, xx), __fmul_rn(yy, yy)),
                         __fmul_rn(zz, zz));
    // store 2-scaled coords: exact (exponent shift)
    C4[j] = make_float4(2.0f * xx, 2.0f * yy, 2.0f * zz, sq);
  }
  if (tid < 72) { int o = tid / 3; fwp[tid] = w_pre[tid] * (g_pre[o] / sqrtf(v_pre[o] + EPS)); }
  if (tid < 24) { float inv = g_pre[tid] / sqrtf(v_pre[tid] + EPS);
                  fbp[tid] = (b_pre[tid] - m_pre[tid]) * inv + be_pre[tid]; }
  for (int j = tid; j < 576; j += 512) { int o = j / 48; fw1[j] = w1[j] * (g1[o] / sqrtf(v1[o] + EPS)); }
  if (tid < 12) { float inv = g1[tid] / sqrtf(v1[tid] + EPS); fb1[tid] = be1[tid] - m1[tid] * inv; }
  for (int j = tid; j < 720; j += 512) { int o = j / 60; fw2[j] = w2[j] * (g2[o] / sqrtf(v2[o] + EPS)); }
  if (tid < 12) { float inv = g2[tid] / sqrtf(v2[tid] + EPS); fb2[tid] = be2[tid] - m2[tid] * inv; }
  for (int j = tid; j < 32 * 20; j += 512) sidx[j] = 0;
  if (tid < 32) scnt[tid] = 0;
  __syncthreads();

  // ---- Step B: pre + aux for this block's 32 points (16 lanes/point) ----
  {
    int r = tid & 15, pt = tid >> 4;
    int n0 = chunk * 32 + pt;
    size_t pgl = (size_t)(b << 11) + n0;
    float x0 = xb[n0], x1 = xb[NPTS + n0], x2 = xb[2 * NPTS + n0];
    float pr[24];
#pragma unroll
    for (int c = 0; c < 24; ++c) {
      float v = fmaf(fwp[c * 3 + 0], x0,
                fmaf(fwp[c * 3 + 1], x1,
                fmaf(fwp[c * 3 + 2], x2, fbp[c])));
      pr[c] = fmaxf(v, 0.f);
    }
    if (r == 0) {   // static indexing only (avoid scratch)
      float4* o4 = (float4*)(pre + pgl * 24);
#pragma unroll
      for (int i = 0; i < 6; ++i)
        o4[i] = make_float4(pr[4*i], pr[4*i+1], pr[4*i+2], pr[4*i+3]);
    }
    if (r < 12) {
      int o = r;
      float u1 = fb1[o], a1 = 0.f, u2 = fb2[o], a2 = 0.f, u3 = 0.f, a3 = 0.f;
#pragma unroll
      for (int i = 0; i < 24; ++i) {
        u1 = fmaf(fw1[o*48 + i],      pr[i], u1);
        a1 = fmaf(fw1[o*48 + 24 + i], pr[i], a1);
        u2 = fmaf(fw2[o*60 + 12 + i], pr[i], u2);
        a2 = fmaf(fw2[o*60 + 36 + i], pr[i], a2);
        u3 = fmaf(w3[o*72 + 24 + i],  pr[i], u3);
        a3 = fmaf(w3[o*72 + 48 + i],  pr[i], a3);
      }
      float* A = aux + pgl * 72;
      A[o] = u1; A[12 + o] = u2; A[24 + o] = u3;
      A[36 + o] = a1; A[48 + o] = a2; A[60 + o] = a3;
    }
  }
  __syncthreads();   // folded-weight area dead; slist region live from here

  // ---- Step C: exact 16-NN, 32 points x 16 slices of 128 candidates ----
  int p = tid & 31, s = tid >> 5;            // point 0..31, slice 0..15
  int n = chunk * 32 + p;
  float4 me4 = C4[n];
  float mex = 0.5f * me4.x, mey = 0.5f * me4.y, mez = 0.5f * me4.z;
  float sqn = me4.w;
  const float4* Cs = C4 + s * 128;
  int selfc = n - s * 128;                   // in [0,128) only for self slice
  // Phase 1: batched top-16 — per 16 candidates: sort (Batcher, 63 CE) + merge
  float L[16];
#pragma unroll
  for (int t = 0; t < 16; ++t) L[t] = BIG;
  for (int c0 = 0; c0 < 128; c0 += 16) {
    float S[16];
#pragma unroll
    for (int cc = 0; cc < 16; ++cc) {
      float4 q = Cs[c0 + cc];
      float d2 = dist2f(mex, mey, mez, sqn, q);
      S[cc] = ((c0 + cc) == selfc) ? BIG : d2;
    }
    // Batcher odd-even mergesort, ascending (all indices compile-time)
#pragma unroll
    for (int pw = 1; pw < 16; pw <<= 1) {
#pragma unroll
      for (int k = pw; k >= 1; k >>= 1) {
#pragma unroll
        for (int j = (k & (pw - 1)); j + k < 16; j += 2 * k) {
#pragma unroll
          for (int i = 0; i < k; ++i) {
            int a = i + j, bq = i + j + k;
            if (bq < 16 && (a / (2 * pw) == bq / (2 * pw))) {
              float lo = fminf(S[a], S[bq]);
              float hi = fmaxf(S[a], S[bq]);
              S[a] = lo; S[bq] = hi;
            }
          }
        }
      }
    }
    // keep-16-smallest merge of sorted L and sorted S (bitonic lower half)
    float m[16];
#pragma unroll
    for (int i = 0; i < 16; ++i) m[i] = fminf(L[i], S[15 - i]);
#pragma unroll
    for (int d = 8; d >= 1; d >>= 1) {
#pragma unroll
      for (int i = 0; i < 16; ++i) {
        if (!(i & d)) {
          float lo = fminf(m[i], m[i | d]);
          float hi = fmaxf(m[i], m[i | d]);
          m[i] = lo; m[i | d] = hi;
        }
      }
    }
#pragma unroll
    for (int i = 0; i < 16; ++i) L[i] = m[i];
  }
  // wave-level merge of slice pairs (s, s^1) via shfl: 16 lists -> 8
  {
    float bb[16], m16[16];
#pragma unroll
    for (int i = 0; i < 16; ++i) bb[i] = __shfl_xor(L[i], 32, 64);
#pragma unroll
    for (int i = 0; i < 16; ++i) m16[i] = fminf(L[i], bb[15 - i]);
#pragma unroll
    for (int d = 8; d >= 1; d >>= 1) {
#pragma unroll
      for (int i = 0; i < 16; ++i) {
        if (!(i & d)) {
          float lo = fminf(m16[i], m16[i | d]);
          float hi = fmaxf(m16[i], m16[i | d]);
          m16[i] = lo; m16[i | d] = hi;
        }
      }
    }
    if (!(s & 1)) {
#pragma unroll
      for (int i = 0; i < 16; ++i) slist[((s >> 1) * 16 + i) * 32 + p] = m16[i];
    }
  }
  __syncthreads();
  // Phase 2: merge tree 8 -> 4 -> 2 -> 1 lists (parallel over points)
  for (int W = 4; W >= 1; W >>= 1) {
    int w = tid >> 5;
    bool act = (w < W);
    float a[16], bb[16];
    if (act) {
#pragma unroll
      for (int i = 0; i < 16; ++i) a[i]  = slist[((2 * w) * 16 + i) * 32 + p];
#pragma unroll
      for (int i = 0; i < 16; ++i) bb[i] = slist[((2 * w + 1) * 16 + i) * 32 + p];
    }
    __syncthreads();
    if (act) {
      float m16[16];
#pragma unroll
      for (int i = 0; i < 16; ++i) m16[i] = fminf(a[i], bb[15 - i]);
#pragma unroll
      for (int d = 8; d >= 1; d >>= 1) {
#pragma unroll
        for (int i = 0; i < 16; ++i) {
          if (!(i & d)) {
            float lo = fminf(m16[i], m16[i | d]);
            float hi = fmaxf(m16[i], m16[i | d]);
            m16[i] = lo; m16[i | d] = hi;
          }
        }
      }
#pragma unroll
      for (int i = 0; i < 16; ++i) slist[(w * 16 + i) * 32 + p] = m16[i];
    }
    __syncthreads();
  }
  float tau = slist[15 * 32 + p];            // exact 16th smallest (self excluded)
  // Phase 3: rescan, collect indices with d2 <= tau (same dist2f -> bit-exact)
#pragma unroll 4
  for (int c = 0; c < 128; ++c) {
    float4 q = Cs[c];
    float d2 = dist2f(mex, mey, mez, sqn, q);
    int j = s * 128 + c;
    if (d2 <= tau && j != n) {
      int pos = atomicAdd(&scnt[p], 1);
      if (pos < 20) { sd2[p * 20 + pos] = d2; sidx[p * 20 + pos] = j; }
    }
  }
  __syncthreads();
  // Phase 4: rare tie fixup — keep 16 smallest by (d2, idx) lexicographic
  if (tid < 32) {
    int c = scnt[tid]; if (c > 20) c = 20;
    if (c > 16) {
      for (int t = 0; t < 16; ++t) {
        int best = t;
        for (int u = t + 1; u < c; ++u) {
          float da = sd2[tid * 20 + u], db = sd2[tid * 20 + best];
          int ia = sidx[tid * 20 + u], ib = sidx[tid * 20 + best];
          if (da < db || (da == db && ia < ib)) best = u;
        }
        float td = sd2[tid * 20 + t]; sd2[tid * 20 + t] = sd2[tid * 20 + best]; sd2[tid * 20 + best] = td;
        int ti = sidx[tid * 20 + t]; sidx[tid * 20 + t] = sidx[tid * 20 + best]; sidx[tid * 20 + best] = ti;
      }
    }
  }
  __syncthreads();
  {
    int pp = tid >> 4, kk = tid & 15;        // 512 threads = 32 pts x 16 nbrs
    knn_out[((size_t)b * NPTS + chunk * 32 + pp) * KNB + kk] = sidx[pp * 20 + kk];
  }
}

// Fused edge-MLP + max. 16 lanes/point; neighbor-dependent 12x12 blocks only.
__global__ __launch_bounds__(256) void mlp_kernel(
    const float* __restrict__ pre, const float* __restrict__ aux,
    const int* __restrict__ knn, const float* __restrict__ x,
    const float* __restrict__ w2, const float* __restrict__ g2,
    const float* __restrict__ v2, const float* __restrict__ w3,
    float* __restrict__ out) {
  __shared__ float sW2h[144], sW3h2[144], sW3h1[144];
  __shared__ float sout[87 * 16];
  int tid = threadIdx.x;
  if (tid < 144) {
    int o = tid / 12, i = tid - o * 12;
    float inv2 = g2[o] / sqrtf(v2[o] + EPS);
    sW2h[tid]  = w2[o * 60 + i] * inv2;
    sW3h2[tid] = w3[o * 72 + i];
    sW3h1[tid] = w3[o * 72 + 12 + i];
  }
  __syncthreads();
  int k = tid & 15, pl = tid >> 4;
  int p = blockIdx.x * 16 + pl;            // 0..16383
  int b = p >> 11, n = p & (NPTS - 1);
  int nb = knn[(size_t)p * KNB + k];
  const float4* u4 = (const float4*)(aux + (size_t)p * 72);
  const float4* a4 = (const float4*)(aux + ((size_t)(b << 11) + nb) * 72 + 36);
  float uc[36], av[36];
#pragma unroll
  for (int i = 0; i < 9; ++i) {
    float4 t = u4[i];
    uc[4*i] = t.x; uc[4*i+1] = t.y; uc[4*i+2] = t.z; uc[4*i+3] = t.w;
    float4 t2 = a4[i];
    av[4*i] = t2.x; av[4*i+1] = t2.y; av[4*i+2] = t2.z; av[4*i+3] = t2.w;
  }
  float h1[12], h2[12], h3[12];
#pragma unroll
  for (int o = 0; o < 12; ++o) h1[o] = fmaxf(uc[o] + av[o], 0.f);
#pragma unroll
  for (int o = 0; o < 12; ++o) {
    float a = uc[12 + o] + av[12 + o];
#pragma unroll
    for (int i = 0; i < 12; ++i) a = fmaf(sW2h[o * 12 + i], h1[i], a);
    h2[o] = fmaxf(a, 0.f);
  }
#pragma unroll
  for (int o = 0; o < 12; ++o) {
    float a = uc[24 + o] + av[24 + o];
#pragma unroll
    for (int i = 0; i < 12; ++i) a = fmaf(sW3h2[o * 12 + i], h2[i], a);
#pragma unroll
    for (int i = 0; i < 12; ++i) a = fmaf(sW3h1[o * 12 + i], h1[i], a);
    h3[o] = a;
  }
  float nbf[24];
  const float4* pn4 = (const float4*)(pre + ((size_t)(b << 11) + nb) * 24);
#pragma unroll
  for (int i = 0; i < 6; ++i) {
    float4 t = pn4[i];
    nbf[4*i] = t.x; nbf[4*i+1] = t.y; nbf[4*i+2] = t.z; nbf[4*i+3] = t.w;
  }
#pragma unroll
  for (int m = 1; m < 16; m <<= 1) {
#pragma unroll
    for (int o = 0; o < 12; ++o) {
      h1[o] = fmaxf(h1[o], __shfl_xor(h1[o], m, 16));
      h2[o] = fmaxf(h2[o], __shfl_xor(h2[o], m, 16));
      h3[o] = fmaxf(h3[o], __shfl_xor(h3[o], m, 16));
    }
#pragma unroll
    for (int i = 0; i < 24; ++i)
      nbf[i] = fmaxf(nbf[i], __shfl_xor(nbf[i], m, 16));
  }
  if (k == 0) {
    const float4* c4 = (const float4*)(pre + (size_t)p * 24);
#pragma unroll
    for (int o = 0; o < 12; ++o) {
      sout[(0  + o) * 16 + pl] = h3[o];
      sout[(12 + o) * 16 + pl] = h2[o];
      sout[(24 + o) * 16 + pl] = h1[o];
    }
#pragma unroll
    for (int i = 0; i < 6; ++i) {
      float4 t = c4[i];
      sout[(36 + 4*i    ) * 16 + pl] = t.x;
      sout[(36 + 4*i + 1) * 16 + pl] = t.y;
      sout[(36 + 4*i + 2) * 16 + pl] = t.z;
      sout[(36 + 4*i + 3) * 16 + pl] = t.w;
    }
#pragma unroll
    for (int i = 0; i < 24; ++i) sout[(60 + i) * 16 + pl] = nbf[i];
    const float* xb = x + (size_t)b * 3 * NPTS + n;
    sout[84 * 16 + pl] = xb[0];
    sout[85 * 16 + pl] = xb[NPTS];
    sout[86 * 16 + pl] = xb[2 * NPTS];
  }
  __syncthreads();
  int n0 = (blockIdx.x * 16) & (NPTS - 1);
  float* ob = out + (size_t)b * 87 * NPTS;
  for (int j2 = tid; j2 < 87 * 16; j2 += 256) {
    int c = j2 >> 4, i = j2 & 15;
    ob[(size_t)c * NPTS + n0 + i] = sout[j2];
  }
}

extern "C" void kernel_launch(void* const* d_in, const int* in_sizes, int n_in,
                              void* d_out, int out_size, void* d_ws, size_t ws_size,
                              hipStream_t stream) {
  (void)in_sizes; (void)n_in; (void)out_size; (void)ws_size;
  const float* x     = (const float*)d_in[0];
  const float* w_pre = (const float*)d_in[1];
  const float* b_pre = (const float*)d_in[2];
  const float* g_pre = (const float*)d_in[3];
  const float* be_pre= (const float*)d_in[4];
  const float* m_pre = (const float*)d_in[5];
  const float* v_pre = (const float*)d_in[6];
  const float* w1    = (const float*)d_in[7];
  const float* g1    = (const float*)d_in[8];
  const float* be1   = (const float*)d_in[9];
  const float* m1    = (const float*)d_in[10];
  const float* v1    = (const float*)d_in[11];
  const float* w2    = (const float*)d_in[12];
  const float* g2    = (const float*)d_in[13];
  const float* be2   = (const float*)d_in[14];
  const float* m2    = (const float*)d_in[15];
  const float* v2    = (const float*)d_in[16];
  const float* w3    = (const float*)d_in[17];
  float* ws  = (float*)d_ws;
  float* pre = ws + WS_PRE;
  float* aux = ws + WS_AUX;
  int*   knn = (int*)(ws + WS_IDX);
  float* out = (float*)d_out;

  fused_kernel<<<KNN_BLKS, 512, FUSED_LDS, stream>>>(
      x, w_pre, b_pre, g_pre, be_pre, m_pre, v_pre,
      w1, g1, be1, m1, v1, w2, g2, be2, m2, v2, w3,
      pre, aux, knn);
  mlp_kernel<<<NBATCH * NPTS / 16, 256, 0, stream>>>(pre, aux, knn, x,
                                                     w2, g2, v2, w3, out);
}

// Round 2
// 155.679 us; speedup vs baseline: 1.1450x; 1.0023x over previous
//
#include <hip/hip_runtime.h>
#include <math.h>

#define EPS 1e-5f
#define NBATCH 8
#define NPTS 2048
#define KNB 16
#define BIG 3.2e38f

#define CHUNK_PTS 16
#define KNN_BLKS (NBATCH * 128)   // 128 chunks of 16 points per batch
#define FUSED_LDS 40960           // 32KB C4 + 8KB shared-lifetime region -> 4 blocks/CU

// ---- workspace layout (in floats) ----
#define WS_PRE 0                            // 16384*24
#define WS_AUX (16384 * 24)                 // 16384*72
#define WS_IDX (WS_AUX + 16384 * 72)        // 16384*16 ints

// Shared by phase 1 and phase 3 — MUST be bitwise identical in both.
__device__ __forceinline__ float dist2f(float mex, float mey, float mez,
                                        float sqn, float4 q) {
  float dot2 = fmaf(mex, q.x, fmaf(mey, q.y, __fmul_rn(mez, q.z)));
  return __fsub_rn(__fadd_rn(sqn, q.w), dot2);
}

// One uniform kernel: every block handles 16 points: pre+aux fold + exact 16-NN.
__global__ __launch_bounds__(512, 8) void fused_kernel(
    const float* __restrict__ x,
    const float* __restrict__ w_pre, const float* __restrict__ b_pre,
    const float* __restrict__ g_pre, const float* __restrict__ be_pre,
    const float* __restrict__ m_pre, const float* __restrict__ v_pre,
    const float* __restrict__ w1, const float* __restrict__ g1,
    const float* __restrict__ be1, const float* __restrict__ m1,
    const float* __restrict__ v1,
    const float* __restrict__ w2, const float* __restrict__ g2,
    const float* __restrict__ be2, const float* __restrict__ m2,
    const float* __restrict__ v2, const float* __restrict__ w3,
    float* __restrict__ pre, float* __restrict__ aux,
    int* __restrict__ knn_out) {
  extern __shared__ char smem[];
  float4* C4   = (float4*)smem;              // [2048] (2x,2y,2z,sq), 32 KB
  float* slist = (float*)(smem + 32768);     // 2048 floats, 8 KB, time-shared:
  // life 1 (until Step-B barrier): folded weights, transposed for bank-free reads
  float* fwp   = slist;                      // 72   [o*3+c]
  float* fbp   = fwp + 72;                   // 24
  float* fw1t  = fbp + 24;                   // 576  [i*12+o] = w1[o*48+i]*inv1
  float* fb1   = fw1t + 576;                 // 12
  float* fw2t  = fb1 + 12;                   // 720  [i*12+o] = w2[o*60+i]*inv2
  float* fb2   = fw2t + 720;                 // 12
  float* fw3t  = fb2 + 12;                   // 576  [i*12+o] = w3[o*72+24+i]
  float* sinv1 = fw3t + 576;                 // 12
  float* sinv2 = sinv1 + 12;                 // 12
  float* sinvP = sinv2 + 12;                 // 24  (total 2040 <= 2048)
  // life 2 (phase 1/2): merge lists [8 lists][16 vals][16 pts]
  // life 3 (after tau): tie buffers
  float* sd2  = slist;                       // [16][20]
  int*   sidx = (int*)(slist + 320);         // [16][20]
  int*   scnt = (int*)(slist + 640);         // [16]

  int tid = threadIdx.x;
  int bi = blockIdx.x;
  int b = bi >> 7, chunk = bi & 127;
  const float* xb = x + (size_t)b * 3 * NPTS;

  // ---- Step A: build C4, precompute BN inverses ----
  for (int j = tid; j < NPTS; j += 512) {
    float xx = xb[j], yy = xb[NPTS + j], zz = xb[2 * NPTS + j];
    float sq = __fadd_rn(__fadd_rn(__fmul_rn(xx, xx), __fmul_rn(yy, yy)),
                         __fmul_rn(zz, zz));
    // store 2-scaled coords: exact (exponent shift)
    C4[j] = make_float4(2.0f * xx, 2.0f * yy, 2.0f * zz, sq);
  }
  if (tid < 24) sinvP[tid] = g_pre[tid] / sqrtf(v_pre[tid] + EPS);
  if (tid < 12) { sinv1[tid] = g1[tid] / sqrtf(v1[tid] + EPS);
                  sinv2[tid] = g2[tid] / sqrtf(v2[tid] + EPS); }
  __syncthreads();
  if (tid < 72) fwp[tid] = w_pre[tid] * sinvP[tid / 3];
  if (tid < 24) fbp[tid] = (b_pre[tid] - m_pre[tid]) * sinvP[tid] + be_pre[tid];
  if (tid < 12) { fb1[tid] = be1[tid] - m1[tid] * sinv1[tid];
                  fb2[tid] = be2[tid] - m2[tid] * sinv2[tid]; }
  for (int j = tid; j < 576; j += 512) { int i = j / 12, o = j - i * 12; fw1t[j] = w1[o * 48 + i] * sinv1[o]; }
  for (int j = tid; j < 720; j += 512) { int i = j / 12, o = j - i * 12; fw2t[j] = w2[o * 60 + i] * sinv2[o]; }
  for (int j = tid; j < 576; j += 512) { int i = j / 12, o = j - i * 12; fw3t[j] = w3[o * 72 + 24 + i]; }
  __syncthreads();

  // ---- Step B: pre + aux for this block's 16 points (32 lanes/point) ----
  {
    int rr = tid & 31, pt = tid >> 5;
    int n0 = chunk * CHUNK_PTS + pt;
    size_t pgl = (size_t)(b << 11) + n0;
    float x0 = xb[n0], x1 = xb[NPTS + n0], x2 = xb[2 * NPTS + n0];
    float pr[24];
#pragma unroll
    for (int c = 0; c < 24; ++c) {
      float v = fmaf(fwp[c * 3 + 0], x0,
                fmaf(fwp[c * 3 + 1], x1,
                fmaf(fwp[c * 3 + 2], x2, fbp[c])));
      pr[c] = fmaxf(v, 0.f);
    }
    if (rr == 16) {   // pre writer on a lane disjoint from aux lanes
      float4* o4 = (float4*)(pre + pgl * 24);
#pragma unroll
      for (int i = 0; i < 6; ++i)
        o4[i] = make_float4(pr[4*i], pr[4*i+1], pr[4*i+2], pr[4*i+3]);
    }
    if (rr < 12) {
      int o = rr;
      float u1 = fb1[o], a1 = 0.f, u2 = fb2[o], a2 = 0.f, u3 = 0.f, a3 = 0.f;
#pragma unroll
      for (int i = 0; i < 24; ++i) {
        u1 = fmaf(fw1t[i * 12 + o],        pr[i], u1);
        a1 = fmaf(fw1t[(24 + i) * 12 + o], pr[i], a1);
        u2 = fmaf(fw2t[(12 + i) * 12 + o], pr[i], u2);
        a2 = fmaf(fw2t[(36 + i) * 12 + o], pr[i], a2);
        u3 = fmaf(fw3t[i * 12 + o],        pr[i], u3);
        a3 = fmaf(fw3t[(24 + i) * 12 + o], pr[i], a3);
      }
      float* A = aux + pgl * 72;
      A[o] = u1; A[12 + o] = u2; A[24 + o] = u3;
      A[36 + o] = a1; A[48 + o] = a2; A[60 + o] = a3;
    }
  }
  __syncthreads();   // folded-weight area dead; slist lists live from here

  // ---- Step C: exact 16-NN, 16 points x 32 slices of 64 candidates ----
  int p = tid & 15, s = tid >> 4;            // point 0..15, slice 0..31
  int n = chunk * CHUNK_PTS + p;
  float4 me4 = C4[n];
  float mex = 0.5f * me4.x, mey = 0.5f * me4.y, mez = 0.5f * me4.z;
  float sqn = me4.w;
  const float4* Cs = C4 + s * 64;
  int selfc = n - s * 64;                    // in [0,64) only for self slice
  // Phase 1: batched top-16 — per 16 candidates: sort (Batcher, 63 CE) + merge
  float L[16];
#pragma unroll
  for (int t = 0; t < 16; ++t) L[t] = BIG;
  for (int c0 = 0; c0 < 64; c0 += 16) {
    float S[16];
#pragma unroll
    for (int cc = 0; cc < 16; ++cc) {
      float4 q = Cs[c0 + cc];
      float d2 = dist2f(mex, mey, mez, sqn, q);
      S[cc] = ((c0 + cc) == selfc) ? BIG : d2;
    }
    // Batcher odd-even mergesort, ascending (all indices compile-time)
#pragma unroll
    for (int pw = 1; pw < 16; pw <<= 1) {
#pragma unroll
      for (int k = pw; k >= 1; k >>= 1) {
#pragma unroll
        for (int j = (k & (pw - 1)); j + k < 16; j += 2 * k) {
#pragma unroll
          for (int i = 0; i < k; ++i) {
            int a = i + j, bq = i + j + k;
            if (bq < 16 && (a / (2 * pw) == bq / (2 * pw))) {
              float lo = fminf(S[a], S[bq]);
              float hi = fmaxf(S[a], S[bq]);
              S[a] = lo; S[bq] = hi;
            }
          }
        }
      }
    }
    // keep-16-smallest merge of sorted L and sorted S (bitonic lower half)
    float m[16];
#pragma unroll
    for (int i = 0; i < 16; ++i) m[i] = fminf(L[i], S[15 - i]);
#pragma unroll
    for (int d = 8; d >= 1; d >>= 1) {
#pragma unroll
      for (int i = 0; i < 16; ++i) {
        if (!(i & d)) {
          float lo = fminf(m[i], m[i | d]);
          float hi = fmaxf(m[i], m[i | d]);
          m[i] = lo; m[i | d] = hi;
        }
      }
    }
#pragma unroll
    for (int i = 0; i < 16; ++i) L[i] = m[i];
  }
  // wave-level merges: slices (s,s^1) then (s,s^2): 32 lists -> 8 (all in-wave)
  {
    float bb[16], m16[16];
#pragma unroll
    for (int i = 0; i < 16; ++i) bb[i] = __shfl_xor(L[i], 16, 64);
#pragma unroll
    for (int i = 0; i < 16; ++i) m16[i] = fminf(L[i], bb[15 - i]);
#pragma unroll
    for (int d = 8; d >= 1; d >>= 1) {
#pragma unroll
      for (int i = 0; i < 16; ++i) {
        if (!(i & d)) {
          float lo = fminf(m16[i], m16[i | d]);
          float hi = fmaxf(m16[i], m16[i | d]);
          m16[i] = lo; m16[i | d] = hi;
        }
      }
    }
#pragma unroll
    for (int i = 0; i < 16; ++i) bb[i] = __shfl_xor(m16[i], 32, 64);
    float m2_[16];
#pragma unroll
    for (int i = 0; i < 16; ++i) m2_[i] = fminf(m16[i], bb[15 - i]);
#pragma unroll
    for (int d = 8; d >= 1; d >>= 1) {
#pragma unroll
      for (int i = 0; i < 16; ++i) {
        if (!(i & d)) {
          float lo = fminf(m2_[i], m2_[i | d]);
          float hi = fmaxf(m2_[i], m2_[i | d]);
          m2_[i] = lo; m2_[i | d] = hi;
        }
      }
    }
    if ((s & 3) == 0) {
#pragma unroll
      for (int i = 0; i < 16; ++i) slist[((s >> 2) * 16 + i) * 16 + p] = m2_[i];
    }
  }
  __syncthreads();
  // Phase 2: merge tree 8 -> 4 -> 2 -> 1 lists (parallel over points)
  for (int W = 4; W >= 1; W >>= 1) {
    int w = tid >> 4;
    bool act = (w < W);
    float a[16], bb[16];
    if (act) {
#pragma unroll
      for (int i = 0; i < 16; ++i) a[i]  = slist[((2 * w) * 16 + i) * 16 + p];
#pragma unroll
      for (int i = 0; i < 16; ++i) bb[i] = slist[((2 * w + 1) * 16 + i) * 16 + p];
    }
    __syncthreads();
    if (act) {
      float m16[16];
#pragma unroll
      for (int i = 0; i < 16; ++i) m16[i] = fminf(a[i], bb[15 - i]);
#pragma unroll
      for (int d = 8; d >= 1; d >>= 1) {
#pragma unroll
        for (int i = 0; i < 16; ++i) {
          if (!(i & d)) {
            float lo = fminf(m16[i], m16[i | d]);
            float hi = fmaxf(m16[i], m16[i | d]);
            m16[i] = lo; m16[i | d] = hi;
          }
        }
      }
#pragma unroll
      for (int i = 0; i < 16; ++i) slist[(w * 16 + i) * 16 + p] = m16[i];
    }
    __syncthreads();
  }
  float tau = slist[15 * 16 + p];            // exact 16th smallest (self excluded)
  __syncthreads();                           // everyone has tau; reuse slist region
  for (int j = tid; j < 16 * 20; j += 512) sidx[j] = 0;
  if (tid < 16) scnt[tid] = 0;
  __syncthreads();
  // Phase 3: rescan, collect indices with d2 <= tau (same dist2f -> bit-exact)
#pragma unroll 4
  for (int c = 0; c < 64; ++c) {
    float4 q = Cs[c];
    float d2 = dist2f(mex, mey, mez, sqn, q);
    int j = s * 64 + c;
    if (d2 <= tau && j != n) {
      int pos = atomicAdd(&scnt[p], 1);
      if (pos < 20) { sd2[p * 20 + pos] = d2; sidx[p * 20 + pos] = j; }
    }
  }
  __syncthreads();
  // Phase 4: rare tie fixup — keep 16 smallest by (d2, idx) lexicographic
  if (tid < 16) {
    int c = scnt[tid]; if (c > 20) c = 20;
    if (c > 16) {
      for (int t = 0; t < 16; ++t) {
        int best = t;
        for (int u = t + 1; u < c; ++u) {
          float da = sd2[tid * 20 + u], db = sd2[tid * 20 + best];
          int ia = sidx[tid * 20 + u], ib = sidx[tid * 20 + best];
          if (da < db || (da == db && ia < ib)) best = u;
        }
        float td = sd2[tid * 20 + t]; sd2[tid * 20 + t] = sd2[tid * 20 + best]; sd2[tid * 20 + best] = td;
        int ti = sidx[tid * 20 + t]; sidx[tid * 20 + t] = sidx[tid * 20 + best]; sidx[tid * 20 + best] = ti;
      }
    }
  }
  __syncthreads();
  if (tid < 256) {
    int pp = tid >> 4, kk = tid & 15;        // 256 threads = 16 pts x 16 nbrs
    knn_out[((size_t)b * NPTS + chunk * CHUNK_PTS + pp) * KNB + kk] = sidx[pp * 20 + kk];
  }
}

// Fused edge-MLP + max. 16 lanes/point; neighbor-dependent 12x12 blocks only.
__global__ __launch_bounds__(256) void mlp_kernel(
    const float* __restrict__ pre, const float* __restrict__ aux,
    const int* __restrict__ knn, const float* __restrict__ x,
    const float* __restrict__ w2, const float* __restrict__ g2,
    const float* __restrict__ v2, const float* __restrict__ w3,
    float* __restrict__ out) {
  __shared__ float sW2h[144], sW3h2[144], sW3h1[144];
  __shared__ float sout[87 * 16];
  int tid = threadIdx.x;
  if (tid < 144) {
    int o = tid / 12, i = tid - o * 12;
    float inv2 = g2[o] / sqrtf(v2[o] + EPS);
    sW2h[tid]  = w2[o * 60 + i] * inv2;
    sW3h2[tid] = w3[o * 72 + i];
    sW3h1[tid] = w3[o * 72 + 12 + i];
  }
  __syncthreads();
  int k = tid & 15, pl = tid >> 4;
  int p = blockIdx.x * 16 + pl;            // 0..16383
  int b = p >> 11, n = p & (NPTS - 1);
  int nb = knn[(size_t)p * KNB + k];
  const float4* u4 = (const float4*)(aux + (size_t)p * 72);
  const float4* a4 = (const float4*)(aux + ((size_t)(b << 11) + nb) * 72 + 36);
  float uc[36], av[36];
#pragma unroll
  for (int i = 0; i < 9; ++i) {
    float4 t = u4[i];
    uc[4*i] = t.x; uc[4*i+1] = t.y; uc[4*i+2] = t.z; uc[4*i+3] = t.w;
    float4 t2 = a4[i];
    av[4*i] = t2.x; av[4*i+1] = t2.y; av[4*i+2] = t2.z; av[4*i+3] = t2.w;
  }
  float h1[12], h2[12], h3[12];
#pragma unroll
  for (int o = 0; o < 12; ++o) h1[o] = fmaxf(uc[o] + av[o], 0.f);
#pragma unroll
  for (int o = 0; o < 12; ++o) {
    float a = uc[12 + o] + av[12 + o];
#pragma unroll
    for (int i = 0; i < 12; ++i) a = fmaf(sW2h[o * 12 + i], h1[i], a);
    h2[o] = fmaxf(a, 0.f);
  }
#pragma unroll
  for (int o = 0; o < 12; ++o) {
    float a = uc[24 + o] + av[24 + o];
#pragma unroll
    for (int i = 0; i < 12; ++i) a = fmaf(sW3h2[o * 12 + i], h2[i], a);
#pragma unroll
    for (int i = 0; i < 12; ++i) a = fmaf(sW3h1[o * 12 + i], h1[i], a);
    h3[o] = a;
  }
  float nbf[24];
  const float4* pn4 = (const float4*)(pre + ((size_t)(b << 11) + nb) * 24);
#pragma unroll
  for (int i = 0; i < 6; ++i) {
    float4 t = pn4[i];
    nbf[4*i] = t.x; nbf[4*i+1] = t.y; nbf[4*i+2] = t.z; nbf[4*i+3] = t.w;
  }
#pragma unroll
  for (int m = 1; m < 16; m <<= 1) {
#pragma unroll
    for (int o = 0; o < 12; ++o) {
      h1[o] = fmaxf(h1[o], __shfl_xor(h1[o], m, 16));
      h2[o] = fmaxf(h2[o], __shfl_xor(h2[o], m, 16));
      h3[o] = fmaxf(h3[o], __shfl_xor(h3[o], m, 16));
    }
#pragma unroll
    for (int i = 0; i < 24; ++i)
      nbf[i] = fmaxf(nbf[i], __shfl_xor(nbf[i], m, 16));
  }
  if (k == 0) {
    const float4* c4 = (const float4*)(pre + (size_t)p * 24);
#pragma unroll
    for (int o = 0; o < 12; ++o) {
      sout[(0  + o) * 16 + pl] = h3[o];
      sout[(12 + o) * 16 + pl] = h2[o];
      sout[(24 + o) * 16 + pl] = h1[o];
    }
#pragma unroll
    for (int i = 0; i < 6; ++i) {
      float4 t = c4[i];
      sout[(36 + 4*i    ) * 16 + pl] = t.x;
      sout[(36 + 4*i + 1) * 16 + pl] = t.y;
      sout[(36 + 4*i + 2) * 16 + pl] = t.z;
      sout[(36 + 4*i + 3) * 16 + pl] = t.w;
    }
#pragma unroll
    for (int i = 0; i < 24; ++i) sout[(60 + i) * 16 + pl] = nbf[i];
    const float* xb = x + (size_t)b * 3 * NPTS + n;
    sout[84 * 16 + pl] = xb[0];
    sout[85 * 16 + pl] = xb[NPTS];
    sout[86 * 16 + pl] = xb[2 * NPTS];
  }
  __syncthreads();
  int n0 = (blockIdx.x * 16) & (NPTS - 1);
  float* ob = out + (size_t)b * 87 * NPTS;
  for (int j2 = tid; j2 < 87 * 16; j2 += 256) {
    int c = j2 >> 4, i = j2 & 15;
    ob[(size_t)c * NPTS + n0 + i] = sout[j2];
  }
}

extern "C" void kernel_launch(void* const* d_in, const int* in_sizes, int n_in,
                              void* d_out, int out_size, void* d_ws, size_t ws_size,
                              hipStream_t stream) {
  (void)in_sizes; (void)n_in; (void)out_size; (void)ws_size;
  const float* x     = (const float*)d_in[0];
  const float* w_pre = (const float*)d_in[1];
  const float* b_pre = (const float*)d_in[2];
  const float* g_pre = (const float*)d_in[3];
  const float* be_pre= (const float*)d_in[4];
  const float* m_pre = (const float*)d_in[5];
  const float* v_pre = (const float*)d_in[6];
  const float* w1    = (const float*)d_in[7];
  const float* g1    = (const float*)d_in[8];
  const float* be1   = (const float*)d_in[9];
  const float* m1    = (const float*)d_in[10];
  const float* v1    = (const float*)d_in[11];
  const float* w2    = (const float*)d_in[12];
  const float* g2    = (const float*)d_in[13];
  const float* be2   = (const float*)d_in[14];
  const float* m2    = (const float*)d_in[15];
  const float* v2    = (const float*)d_in[16];
  const float* w3    = (const float*)d_in[17];
  float* ws  = (float*)d_ws;
  float* pre = ws + WS_PRE;
  float* aux = ws + WS_AUX;
  int*   knn = (int*)(ws + WS_IDX);
  float* out = (float*)d_out;

  fused_kernel<<<KNN_BLKS, 512, FUSED_LDS, stream>>>(
      x, w_pre, b_pre, g_pre, be_pre, m_pre, v_pre,
      w1, g1, be1, m1, v1, w2, g2, be2, m2, v2, w3,
      pre, aux, knn);
  mlp_kernel<<<NBATCH * NPTS / 16, 256, 0, stream>>>(pre, aux, knn, x,
                                                     w2, g2, v2, w3, out);
}

// Round 3
// 154.959 us; speedup vs baseline: 1.1503x; 1.0046x over previous
//
#include <hip/hip_runtime.h>
#include <math.h>

#define EPS 1e-5f
#define NBATCH 8
#define NPTS 2048
#define KNB 16
#define BIG 3.2e38f

#define CHUNK_PTS 32
#define KNN_BLKS (NBATCH * 64)    // 64 chunks of 32 points per batch
#define THREADS 1024
#define FUSED_LDS 65536           // 32KB C4 + 32KB time-shared -> 2 blocks/CU (32 waves)

// ---- workspace layout (in floats) ----
#define WS_PRE 0                            // 16384*24
#define WS_AUX (16384 * 24)                 // 16384*72
#define WS_IDX (WS_AUX + 16384 * 72)        // 16384*16 ints

// Shared by phase 1 and phase 3 — MUST be bitwise identical in both.
__device__ __forceinline__ float dist2f(float mex, float mey, float mez,
                                        float sqn, float4 q) {
  float dot2 = fmaf(mex, q.x, fmaf(mey, q.y, __fmul_rn(mez, q.z)));
  return __fsub_rn(__fadd_rn(sqn, q.w), dot2);
}

// One uniform kernel: every block handles 32 points: pre+aux fold + exact 16-NN.
// 1024 threads = 16 waves; each wave holds 2 slices (free 2-way -> rotated to 0-way).
__global__ __launch_bounds__(THREADS, 8) void fused_kernel(
    const float* __restrict__ x,
    const float* __restrict__ w_pre, const float* __restrict__ b_pre,
    const float* __restrict__ g_pre, const float* __restrict__ be_pre,
    const float* __restrict__ m_pre, const float* __restrict__ v_pre,
    const float* __restrict__ w1, const float* __restrict__ g1,
    const float* __restrict__ be1, const float* __restrict__ m1,
    const float* __restrict__ v1,
    const float* __restrict__ w2, const float* __restrict__ g2,
    const float* __restrict__ be2, const float* __restrict__ m2,
    const float* __restrict__ v2, const float* __restrict__ w3,
    float* __restrict__ pre, float* __restrict__ aux,
    int* __restrict__ knn_out) {
  extern __shared__ char smem[];
  float4* C4   = (float4*)smem;              // [2048] (2x,2y,2z,sq), 32 KB
  float* slist = (float*)(smem + 32768);     // 8192 floats, 32 KB, time-shared:
  // life 1 (until Step-B barrier): folded weights, transposed for bank-free reads
  float* fwp   = slist;                      // 72   [o*3+c]
  float* fbp   = fwp + 72;                   // 24
  float* fw1t  = fbp + 24;                   // 576  [i*12+o] = w1[o*48+i]*inv1
  float* fb1   = fw1t + 576;                 // 12
  float* fw2t  = fb1 + 12;                   // 720  [i*12+o] = w2[o*60+i]*inv2
  float* fb2   = fw2t + 720;                 // 12
  float* fw3t  = fb2 + 12;                   // 576  [i*12+o] = w3[o*72+24+i]
  float* sinv1 = fw3t + 576;                 // 12
  float* sinv2 = sinv1 + 12;                 // 12
  float* sinvP = sinv2 + 12;                 // 24  (total 2040)
  // life 2 (phase 1/2): merge lists [16 lists][16 vals][32 pts] = 8192 floats
  // life 3 (after tau): tie buffers
  float* sd2  = slist;                       // [32][20]
  int*   sidx = (int*)(slist + 640);         // [32][20]
  int*   scnt = (int*)(slist + 1280);        // [32]

  int tid = threadIdx.x;
  int bi = blockIdx.x;
  int b = bi >> 6, chunk = bi & 63;
  const float* xb = x + (size_t)b * 3 * NPTS;

  // ---- Step A: build C4, precompute BN inverses ----
  for (int j = tid; j < NPTS; j += THREADS) {
    float xx = xb[j], yy = xb[NPTS + j], zz = xb[2 * NPTS + j];
    float sq = __fadd_rn(__fadd_rn(__fmul_rn(xx, xx), __fmul_rn(yy, yy)),
                         __fmul_rn(zz, zz));
    // store 2-scaled coords: exact (exponent shift)
    C4[j] = make_float4(2.0f * xx, 2.0f * yy, 2.0f * zz, sq);
  }
  if (tid < 24) sinvP[tid] = g_pre[tid] / sqrtf(v_pre[tid] + EPS);
  if (tid < 12) { sinv1[tid] = g1[tid] / sqrtf(v1[tid] + EPS);
                  sinv2[tid] = g2[tid] / sqrtf(v2[tid] + EPS); }
  __syncthreads();
  if (tid < 72) fwp[tid] = w_pre[tid] * sinvP[tid / 3];
  if (tid < 24) fbp[tid] = (b_pre[tid] - m_pre[tid]) * sinvP[tid] + be_pre[tid];
  if (tid < 12) { fb1[tid] = be1[tid] - m1[tid] * sinv1[tid];
                  fb2[tid] = be2[tid] - m2[tid] * sinv2[tid]; }
  if (tid < 576) { int i = tid / 12, o = tid - i * 12; fw1t[tid] = w1[o * 48 + i] * sinv1[o]; }
  if (tid < 720) { int i = tid / 12, o = tid - i * 12; fw2t[tid] = w2[o * 60 + i] * sinv2[o]; }
  if (tid < 576) { int i = tid / 12, o = tid - i * 12; fw3t[tid] = w3[o * 72 + 24 + i]; }
  __syncthreads();

  // ---- Step B: pre + aux for this block's 32 points (32 lanes/point) ----
  {
    int rr = tid & 31, pt = tid >> 5;
    int n0 = chunk * CHUNK_PTS + pt;
    size_t pgl = (size_t)(b << 11) + n0;
    float x0 = xb[n0], x1 = xb[NPTS + n0], x2 = xb[2 * NPTS + n0];
    float pr[24];
#pragma unroll
    for (int c = 0; c < 24; ++c) {
      float v = fmaf(fwp[c * 3 + 0], x0,
                fmaf(fwp[c * 3 + 1], x1,
                fmaf(fwp[c * 3 + 2], x2, fbp[c])));
      pr[c] = fmaxf(v, 0.f);
    }
    if (rr == 16) {   // pre writer on a lane disjoint from aux lanes
      float4* o4 = (float4*)(pre + pgl * 24);
#pragma unroll
      for (int i = 0; i < 6; ++i)
        o4[i] = make_float4(pr[4*i], pr[4*i+1], pr[4*i+2], pr[4*i+3]);
    }
    if (rr < 12) {
      int o = rr;
      float u1 = fb1[o], a1 = 0.f, u2 = fb2[o], a2 = 0.f, u3 = 0.f, a3 = 0.f;
#pragma unroll
      for (int i = 0; i < 24; ++i) {
        u1 = fmaf(fw1t[i * 12 + o],        pr[i], u1);
        a1 = fmaf(fw1t[(24 + i) * 12 + o], pr[i], a1);
        u2 = fmaf(fw2t[(12 + i) * 12 + o], pr[i], u2);
        a2 = fmaf(fw2t[(36 + i) * 12 + o], pr[i], a2);
        u3 = fmaf(fw3t[i * 12 + o],        pr[i], u3);
        a3 = fmaf(fw3t[(24 + i) * 12 + o], pr[i], a3);
      }
      float* A = aux + pgl * 72;
      A[o] = u1; A[12 + o] = u2; A[24 + o] = u3;
      A[36 + o] = a1; A[48 + o] = a2; A[60 + o] = a3;
    }
  }
  __syncthreads();   // folded-weight area dead; slist lists live from here

  // ---- Step C: exact 16-NN, 32 points x 32 slices of 64 candidates ----
  int p = tid & 31, s = tid >> 5;            // point 0..31, slice 0..31
  int n = chunk * CHUNK_PTS + p;
  float4 me4 = C4[n];
  float mex = 0.5f * me4.x, mey = 0.5f * me4.y, mez = 0.5f * me4.z;
  float sqn = me4.w;
  const float4* Cs = C4 + s * 64;
  int selfc = n - s * 64;                    // in [0,64) only for self slice
  int rot = (s & 1) << 2;                    // odd slice reads c^4: distinct bank quad
  // Phase 1: batched top-16 — per 16 candidates: sort (Batcher, 63 CE) + merge
  float L[16];
#pragma unroll
  for (int t = 0; t < 16; ++t) L[t] = BIG;
  for (int c0 = 0; c0 < 64; c0 += 16) {
    float S[16];
#pragma unroll
    for (int cc = 0; cc < 16; ++cc) {
      int c2 = (c0 + cc) ^ rot;
      float4 q = Cs[c2];
      float d2 = dist2f(mex, mey, mez, sqn, q);
      S[cc] = (c2 == selfc) ? BIG : d2;
    }
    // Batcher odd-even mergesort, ascending (all indices compile-time)
#pragma unroll
    for (int pw = 1; pw < 16; pw <<= 1) {
#pragma unroll
      for (int k = pw; k >= 1; k >>= 1) {
#pragma unroll
        for (int j = (k & (pw - 1)); j + k < 16; j += 2 * k) {
#pragma unroll
          for (int i = 0; i < k; ++i) {
            int a = i + j, bq = i + j + k;
            if (bq < 16 && (a / (2 * pw) == bq / (2 * pw))) {
              float lo = fminf(S[a], S[bq]);
              float hi = fmaxf(S[a], S[bq]);
              S[a] = lo; S[bq] = hi;
            }
          }
        }
      }
    }
    // keep-16-smallest merge of sorted L and sorted S (bitonic lower half)
    float m[16];
#pragma unroll
    for (int i = 0; i < 16; ++i) m[i] = fminf(L[i], S[15 - i]);
#pragma unroll
    for (int d = 8; d >= 1; d >>= 1) {
#pragma unroll
      for (int i = 0; i < 16; ++i) {
        if (!(i & d)) {
          float lo = fminf(m[i], m[i | d]);
          float hi = fmaxf(m[i], m[i | d]);
          m[i] = lo; m[i | d] = hi;
        }
      }
    }
#pragma unroll
    for (int i = 0; i < 16; ++i) L[i] = m[i];
  }
  // in-wave merge: the wave's two slices (lanes l and l^32 share point p)
  {
    float bb[16], m16[16];
#pragma unroll
    for (int i = 0; i < 16; ++i) bb[i] = __shfl_xor(L[i], 32, 64);
#pragma unroll
    for (int i = 0; i < 16; ++i) m16[i] = fminf(L[i], bb[15 - i]);
#pragma unroll
    for (int d = 8; d >= 1; d >>= 1) {
#pragma unroll
      for (int i = 0; i < 16; ++i) {
        if (!(i & d)) {
          float lo = fminf(m16[i], m16[i | d]);
          float hi = fmaxf(m16[i], m16[i | d]);
          m16[i] = lo; m16[i | d] = hi;
        }
      }
    }
    int w = tid >> 6;                        // wave id 0..15
    if (!(s & 1)) {                          // lanes 0..31 of each wave
#pragma unroll
      for (int i = 0; i < 16; ++i) slist[(w * 16 + i) * 32 + p] = m16[i];
    }
  }
  __syncthreads();
  // Phase 2: merge tree 16 -> 8 -> 4 -> 2 -> 1 lists (shfl-assisted, per wave)
  for (int W = 8; W >= 1; W >>= 1) {
    int w = tid >> 6;
    int h = (tid >> 5) & 1;
    bool act = (w < W);
    float val[16];
    if (act) {
#pragma unroll
      for (int i = 0; i < 16; ++i) val[i] = slist[((2 * w + h) * 16 + i) * 32 + p];
    }
    __syncthreads();
    if (act) {
      float bb[16], m16[16];
#pragma unroll
      for (int i = 0; i < 16; ++i) bb[i] = __shfl_xor(val[i], 32, 64);
#pragma unroll
      for (int i = 0; i < 16; ++i) m16[i] = fminf(val[i], bb[15 - i]);
#pragma unroll
      for (int d = 8; d >= 1; d >>= 1) {
#pragma unroll
        for (int i = 0; i < 16; ++i) {
          if (!(i & d)) {
            float lo = fminf(m16[i], m16[i | d]);
            float hi = fmaxf(m16[i], m16[i | d]);
            m16[i] = lo; m16[i | d] = hi;
          }
        }
      }
      if (h == 0) {
#pragma unroll
        for (int i = 0; i < 16; ++i) slist[(w * 16 + i) * 32 + p] = m16[i];
      }
    }
    __syncthreads();
  }
  float tau = slist[15 * 32 + p];            // exact 16th smallest (self excluded)
  __syncthreads();                           // everyone has tau; reuse slist region
  for (int j = tid; j < 32 * 20; j += THREADS) sidx[j] = 0;
  if (tid < 32) scnt[tid] = 0;
  __syncthreads();
  // Phase 3: rescan, collect indices with d2 <= tau (same dist2f -> bit-exact)
#pragma unroll 4
  for (int c = 0; c < 64; ++c) {
    int c2 = c ^ rot;
    float4 q = Cs[c2];
    float d2 = dist2f(mex, mey, mez, sqn, q);
    int j = s * 64 + c2;
    if (d2 <= tau && j != n) {
      int pos = atomicAdd(&scnt[p], 1);
      if (pos < 20) { sd2[p * 20 + pos] = d2; sidx[p * 20 + pos] = j; }
    }
  }
  __syncthreads();
  // Phase 4: rare tie fixup — keep 16 smallest by (d2, idx) lexicographic
  if (tid < 32) {
    int c = scnt[tid]; if (c > 20) c = 20;
    if (c > 16) {
      for (int t = 0; t < 16; ++t) {
        int best = t;
        for (int u = t + 1; u < c; ++u) {
          float da = sd2[tid * 20 + u], db = sd2[tid * 20 + best];
          int ia = sidx[tid * 20 + u], ib = sidx[tid * 20 + best];
          if (da < db || (da == db && ia < ib)) best = u;
        }
        float td = sd2[tid * 20 + t]; sd2[tid * 20 + t] = sd2[tid * 20 + best]; sd2[tid * 20 + best] = td;
        int ti = sidx[tid * 20 + t]; sidx[tid * 20 + t] = sidx[tid * 20 + best]; sidx[tid * 20 + best] = ti;
      }
    }
  }
  __syncthreads();
  if (tid < 512) {
    int pp = tid >> 4, kk = tid & 15;        // 512 threads = 32 pts x 16 nbrs
    knn_out[((size_t)b * NPTS + chunk * CHUNK_PTS + pp) * KNB + kk] = sidx[pp * 20 + kk];
  }
}

// Fused edge-MLP + max. 16 lanes/point; neighbor-dependent 12x12 blocks only.
__global__ __launch_bounds__(256) void mlp_kernel(
    const float* __restrict__ pre, const float* __restrict__ aux,
    const int* __restrict__ knn, const float* __restrict__ x,
    const float* __restrict__ w2, const float* __restrict__ g2,
    const float* __restrict__ v2, const float* __restrict__ w3,
    float* __restrict__ out) {
  __shared__ float sW2h[144], sW3h2[144], sW3h1[144];
  __shared__ float sout[87 * 16];
  int tid = threadIdx.x;
  if (tid < 144) {
    int o = tid / 12, i = tid - o * 12;
    float inv2 = g2[o] / sqrtf(v2[o] + EPS);
    sW2h[tid]  = w2[o * 60 + i] * inv2;
    sW3h2[tid] = w3[o * 72 + i];
    sW3h1[tid] = w3[o * 72 + 12 + i];
  }
  __syncthreads();
  int k = tid & 15, pl = tid >> 4;
  int p = blockIdx.x * 16 + pl;            // 0..16383
  int b = p >> 11, n = p & (NPTS - 1);
  int nb = knn[(size_t)p * KNB + k];
  const float4* u4 = (const float4*)(aux + (size_t)p * 72);
  const float4* a4 = (const float4*)(aux + ((size_t)(b << 11) + nb) * 72 + 36);
  float uc[36], av[36];
#pragma unroll
  for (int i = 0; i < 9; ++i) {
    float4 t = u4[i];
    uc[4*i] = t.x; uc[4*i+1] = t.y; uc[4*i+2] = t.z; uc[4*i+3] = t.w;
    float4 t2 = a4[i];
    av[4*i] = t2.x; av[4*i+1] = t2.y; av[4*i+2] = t2.z; av[4*i+3] = t2.w;
  }
  float h1[12], h2[12], h3[12];
#pragma unroll
  for (int o = 0; o < 12; ++o) h1[o] = fmaxf(uc[o] + av[o], 0.f);
#pragma unroll
  for (int o = 0; o < 12; ++o) {
    float a = uc[12 + o] + av[12 + o];
#pragma unroll
    for (int i = 0; i < 12; ++i) a = fmaf(sW2h[o * 12 + i], h1[i], a);
    h2[o] = fmaxf(a, 0.f);
  }
#pragma unroll
  for (int o = 0; o < 12; ++o) {
    float a = uc[24 + o] + av[24 + o];
#pragma unroll
    for (int i = 0; i < 12; ++i) a = fmaf(sW3h2[o * 12 + i], h2[i], a);
#pragma unroll
    for (int i = 0; i < 12; ++i) a = fmaf(sW3h1[o * 12 + i], h1[i], a);
    h3[o] = a;
  }
  float nbf[24];
  const float4* pn4 = (const float4*)(pre + ((size_t)(b << 11) + nb) * 24);
#pragma unroll
  for (int i = 0; i < 6; ++i) {
    float4 t = pn4[i];
    nbf[4*i] = t.x; nbf[4*i+1] = t.y; nbf[4*i+2] = t.z; nbf[4*i+3] = t.w;
  }
#pragma unroll
  for (int m = 1; m < 16; m <<= 1) {
#pragma unroll
    for (int o = 0; o < 12; ++o) {
      h1[o] = fmaxf(h1[o], __shfl_xor(h1[o], m, 16));
      h2[o] = fmaxf(h2[o], __shfl_xor(h2[o], m, 16));
      h3[o] = fmaxf(h3[o], __shfl_xor(h3[o], m, 16));
    }
#pragma unroll
    for (int i = 0; i < 24; ++i)
      nbf[i] = fmaxf(nbf[i], __shfl_xor(nbf[i], m, 16));
  }
  if (k == 0) {
    const float4* c4 = (const float4*)(pre + (size_t)p * 24);
#pragma unroll
    for (int o = 0; o < 12; ++o) {
      sout[(0  + o) * 16 + pl] = h3[o];
      sout[(12 + o) * 16 + pl] = h2[o];
      sout[(24 + o) * 16 + pl] = h1[o];
    }
#pragma unroll
    for (int i = 0; i < 6; ++i) {
      float4 t = c4[i];
      sout[(36 + 4*i    ) * 16 + pl] = t.x;
      sout[(36 + 4*i + 1) * 16 + pl] = t.y;
      sout[(36 + 4*i + 2) * 16 + pl] = t.z;
      sout[(36 + 4*i + 3) * 16 + pl] = t.w;
    }
#pragma unroll
    for (int i = 0; i < 24; ++i) sout[(60 + i) * 16 + pl] = nbf[i];
    const float* xb = x + (size_t)b * 3 * NPTS + n;
    sout[84 * 16 + pl] = xb[0];
    sout[85 * 16 + pl] = xb[NPTS];
    sout[86 * 16 + pl] = xb[2 * NPTS];
  }
  __syncthreads();
  int n0 = (blockIdx.x * 16) & (NPTS - 1);
  float* ob = out + (size_t)b * 87 * NPTS;
  for (int j2 = tid; j2 < 87 * 16; j2 += 256) {
    int c = j2 >> 4, i = j2 & 15;
    ob[(size_t)c * NPTS + n0 + i] = sout[j2];
  }
}

extern "C" void kernel_launch(void* const* d_in, const int* in_sizes, int n_in,
                              void* d_out, int out_size, void* d_ws, size_t ws_size,
                              hipStream_t stream) {
  (void)in_sizes; (void)n_in; (void)out_size; (void)ws_size;
  const float* x     = (const float*)d_in[0];
  const float* w_pre = (const float*)d_in[1];
  const float* b_pre = (const float*)d_in[2];
  const float* g_pre = (const float*)d_in[3];
  const float* be_pre= (const float*)d_in[4];
  const float* m_pre = (const float*)d_in[5];
  const float* v_pre = (const float*)d_in[6];
  const float* w1    = (const float*)d_in[7];
  const float* g1    = (const float*)d_in[8];
  const float* be1   = (const float*)d_in[9];
  const float* m1    = (const float*)d_in[10];
  const float* v1    = (const float*)d_in[11];
  const float* w2    = (const float*)d_in[12];
  const float* g2    = (const float*)d_in[13];
  const float* be2   = (const float*)d_in[14];
  const float* m2    = (const float*)d_in[15];
  const float* v2    = (const float*)d_in[16];
  const float* w3    = (const float*)d_in[17];
  float* ws  = (float*)d_ws;
  float* pre = ws + WS_PRE;
  float* aux = ws + WS_AUX;
  int*   knn = (int*)(ws + WS_IDX);
  float* out = (float*)d_out;

  fused_kernel<<<KNN_BLKS, THREADS, FUSED_LDS, stream>>>(
      x, w_pre, b_pre, g_pre, be_pre, m_pre, v_pre,
      w1, g1, be1, m1, v1, w2, g2, be2, m2, v2, w3,
      pre, aux, knn);
  mlp_kernel<<<NBATCH * NPTS / 16, 256, 0, stream>>>(pre, aux, knn, x,
                                                     w2, g2, v2, w3, out);
}

// Round 4
// 151.537 us; speedup vs baseline: 1.1763x; 1.0226x over previous
//
#include <hip/hip_runtime.h>
#include <math.h>

#define EPS 1e-5f
#define NBATCH 8
#define NPTS 2048
#define KNB 16
#define BIG 3.2e38f

#define CHUNK_PTS 32
#define KNN_BLKS (NBATCH * 64)    // 64 chunks of 32 points per batch
#define THREADS 512
#define FUSED_LDS 49152           // 32KB C4 + 16KB time-shared -> 3 blocks/CU (24 waves)

// ---- workspace layout (in floats) ----
#define WS_PRE 0                            // 16384*24
#define WS_AUX (16384 * 24)                 // 16384*72
#define WS_IDX (WS_AUX + 16384 * 72)        // 16384*16 ints

// Shared by phase 1 and phase 3 — MUST be bitwise identical in both.
__device__ __forceinline__ float dist2f(float mex, float mey, float mez,
                                        float sqn, float4 q) {
  float dot2 = fmaf(mex, q.x, fmaf(mey, q.y, __fmul_rn(mez, q.z)));
  return __fsub_rn(__fadd_rn(sqn, q.w), dot2);
}

// Phase-1 scan of one 128-candidate slice, merging into sorted L[16].
// HASSELF=false skips the per-candidate self mask (only 1 of 8 waves needs it).
template <bool HASSELF>
__device__ __forceinline__ void scan_slice(const float4* __restrict__ Cs, int selfc,
                                           float mex, float mey, float mez,
                                           float sqn, float L[16]) {
  for (int c0 = 0; c0 < 128; c0 += 16) {
    float S[16];
#pragma unroll
    for (int cc = 0; cc < 16; ++cc) {
      float4 q = Cs[c0 + cc];
      float d2 = dist2f(mex, mey, mez, sqn, q);
      if (HASSELF) S[cc] = ((c0 + cc) == selfc) ? BIG : d2;
      else         S[cc] = d2;
    }
    // Batcher odd-even mergesort, ascending (all indices compile-time)
#pragma unroll
    for (int pw = 1; pw < 16; pw <<= 1) {
#pragma unroll
      for (int k = pw; k >= 1; k >>= 1) {
#pragma unroll
        for (int j = (k & (pw - 1)); j + k < 16; j += 2 * k) {
#pragma unroll
          for (int i = 0; i < k; ++i) {
            int a = i + j, bq = i + j + k;
            if (bq < 16 && (a / (2 * pw) == bq / (2 * pw))) {
              float lo = fminf(S[a], S[bq]);
              float hi = fmaxf(S[a], S[bq]);
              S[a] = lo; S[bq] = hi;
            }
          }
        }
      }
    }
    // keep-16-smallest merge of sorted L and sorted S (bitonic lower half)
    float m[16];
#pragma unroll
    for (int i = 0; i < 16; ++i) m[i] = fminf(L[i], S[15 - i]);
#pragma unroll
    for (int d = 8; d >= 1; d >>= 1) {
#pragma unroll
      for (int i = 0; i < 16; ++i) {
        if (!(i & d)) {
          float lo = fminf(m[i], m[i | d]);
          float hi = fmaxf(m[i], m[i | d]);
          m[i] = lo; m[i | d] = hi;
        }
      }
    }
#pragma unroll
    for (int i = 0; i < 16; ++i) L[i] = m[i];
  }
}

// One uniform kernel: every block handles 32 points: pre+aux fold + exact 16-NN.
// 512 threads = 8 waves; each wave holds 2 slices of 128 (2-way broadcast = free).
__global__ __launch_bounds__(THREADS, 6) void fused_kernel(
    const float* __restrict__ x,
    const float* __restrict__ w_pre, const float* __restrict__ b_pre,
    const float* __restrict__ g_pre, const float* __restrict__ be_pre,
    const float* __restrict__ m_pre, const float* __restrict__ v_pre,
    const float* __restrict__ w1, const float* __restrict__ g1,
    const float* __restrict__ be1, const float* __restrict__ m1,
    const float* __restrict__ v1,
    const float* __restrict__ w2, const float* __restrict__ g2,
    const float* __restrict__ be2, const float* __restrict__ m2,
    const float* __restrict__ v2, const float* __restrict__ w3,
    float* __restrict__ pre, float* __restrict__ aux,
    int* __restrict__ knn_out) {
  extern __shared__ char smem[];
  float4* C4   = (float4*)smem;              // [2048] (2x,2y,2z,sq), 32 KB
  float* slist = (float*)(smem + 32768);     // 4096 floats, 16 KB, time-shared:
  // life 1 (until Step-B barrier): folded weights, transposed for bank-free reads
  float* fwp   = slist;                      // 72   [o*3+c]
  float* fbp   = fwp + 72;                   // 24
  float* fw1t  = fbp + 24;                   // 576  [i*12+o] = w1[o*48+i]*inv1
  float* fb1   = fw1t + 576;                 // 12
  float* fw2t  = fb1 + 12;                   // 720  [i*12+o] = w2[o*60+i]*inv2
  float* fb2   = fw2t + 720;                 // 12
  float* fw3t  = fb2 + 12;                   // 576  [i*12+o] = w3[o*72+24+i]
  float* sinv1 = fw3t + 576;                 // 12
  float* sinv2 = sinv1 + 12;                 // 12
  float* sinvP = sinv2 + 12;                 // 24  (total 2040)
  // life 2 (phase 1/2): merge lists [8 lists][16 vals][32 pts] = 4096 floats
  // life 3 (after tau): tie buffers
  float* sd2  = slist;                       // [32][20]
  int*   sidx = (int*)(slist + 640);         // [32][20]
  int*   scnt = (int*)(slist + 1280);        // [32]

  int tid = threadIdx.x;
  int bi = blockIdx.x;
  int b = bi >> 6, chunk = bi & 63;
  const float* xb = x + (size_t)b * 3 * NPTS;

  // ---- Step A: build C4, precompute BN inverses ----
  for (int j = tid; j < NPTS; j += THREADS) {
    float xx = xb[j], yy = xb[NPTS + j], zz = xb[2 * NPTS + j];
    float sq = __fadd_rn(__fadd_rn(__fmul_rn(xx, xx), __fmul_rn(yy, yy)),
                         __fmul_rn(zz, zz));
    // store 2-scaled coords: exact (exponent shift)
    C4[j] = make_float4(2.0f * xx, 2.0f * yy, 2.0f * zz, sq);
  }
  if (tid < 24) sinvP[tid] = g_pre[tid] / sqrtf(v_pre[tid] + EPS);
  if (tid < 12) { sinv1[tid] = g1[tid] / sqrtf(v1[tid] + EPS);
                  sinv2[tid] = g2[tid] / sqrtf(v2[tid] + EPS); }
  __syncthreads();
  if (tid < 72) fwp[tid] = w_pre[tid] * sinvP[tid / 3];
  if (tid < 24) fbp[tid] = (b_pre[tid] - m_pre[tid]) * sinvP[tid] + be_pre[tid];
  if (tid < 12) { fb1[tid] = be1[tid] - m1[tid] * sinv1[tid];
                  fb2[tid] = be2[tid] - m2[tid] * sinv2[tid]; }
  for (int j = tid; j < 576; j += THREADS) { int i = j / 12, o = j - i * 12; fw1t[j] = w1[o * 48 + i] * sinv1[o]; }
  for (int j = tid; j < 720; j += THREADS) { int i = j / 12, o = j - i * 12; fw2t[j] = w2[o * 60 + i] * sinv2[o]; }
  for (int j = tid; j < 576; j += THREADS) { int i = j / 12, o = j - i * 12; fw3t[j] = w3[o * 72 + 24 + i]; }
  __syncthreads();

  // ---- Step B: pre + aux for this block's 32 points (16 lanes/point) ----
  {
    int r = tid & 15, pt = tid >> 4;
    int n0 = chunk * CHUNK_PTS + pt;
    size_t pgl = (size_t)(b << 11) + n0;
    float x0 = xb[n0], x1 = xb[NPTS + n0], x2 = xb[2 * NPTS + n0];
    float pr[24];
#pragma unroll
    for (int c = 0; c < 24; ++c) {
      float v = fmaf(fwp[c * 3 + 0], x0,
                fmaf(fwp[c * 3 + 1], x1,
                fmaf(fwp[c * 3 + 2], x2, fbp[c])));
      pr[c] = fmaxf(v, 0.f);
    }
    if (r == 12) {   // pre writer on a lane disjoint from aux lanes
      float4* o4 = (float4*)(pre + pgl * 24);
#pragma unroll
      for (int i = 0; i < 6; ++i)
        o4[i] = make_float4(pr[4*i], pr[4*i+1], pr[4*i+2], pr[4*i+3]);
    }
    if (r < 12) {
      int o = r;
      float u1 = fb1[o], a1 = 0.f, u2 = fb2[o], a2 = 0.f, u3 = 0.f, a3 = 0.f;
#pragma unroll
      for (int i = 0; i < 24; ++i) {
        u1 = fmaf(fw1t[i * 12 + o],        pr[i], u1);
        a1 = fmaf(fw1t[(24 + i) * 12 + o], pr[i], a1);
        u2 = fmaf(fw2t[(12 + i) * 12 + o], pr[i], u2);
        a2 = fmaf(fw2t[(36 + i) * 12 + o], pr[i], a2);
        u3 = fmaf(fw3t[i * 12 + o],        pr[i], u3);
        a3 = fmaf(fw3t[(24 + i) * 12 + o], pr[i], a3);
      }
      float* A = aux + pgl * 72;
      A[o] = u1; A[12 + o] = u2; A[24 + o] = u3;
      A[36 + o] = a1; A[48 + o] = a2; A[60 + o] = a3;
    }
  }
  __syncthreads();   // folded-weight area dead; slist lists live from here

  // ---- Step C: exact 16-NN, 32 points x 16 slices of 128 candidates ----
  int p = tid & 31, s = tid >> 5;            // point 0..31, slice 0..15
  int w = tid >> 6;                          // wave 0..7 (slices 2w, 2w+1)
  int n = chunk * CHUNK_PTS + p;
  float4 me4 = C4[n];
  float mex = 0.5f * me4.x, mey = 0.5f * me4.y, mez = 0.5f * me4.z;
  float sqn = me4.w;
  const float4* Cs = C4 + s * 128;
  int selfc = n - s * 128;                   // in [0,128) only for self slice
  int wself = chunk >> 3;                    // wave whose slice pair holds the self slice
  // Phase 1: batched top-16; self mask only in the self wave
  float L[16];
#pragma unroll
  for (int t = 0; t < 16; ++t) L[t] = BIG;
  if (w == wself) scan_slice<true >(Cs, selfc, mex, mey, mez, sqn, L);
  else            scan_slice<false>(Cs, selfc, mex, mey, mez, sqn, L);
  // in-wave merge: the wave's two slices (lanes l and l^32 share point p)
  {
    float bb[16], m16[16];
#pragma unroll
    for (int i = 0; i < 16; ++i) bb[i] = __shfl_xor(L[i], 32, 64);
#pragma unroll
    for (int i = 0; i < 16; ++i) m16[i] = fminf(L[i], bb[15 - i]);
#pragma unroll
    for (int d = 8; d >= 1; d >>= 1) {
#pragma unroll
      for (int i = 0; i < 16; ++i) {
        if (!(i & d)) {
          float lo = fminf(m16[i], m16[i | d]);
          float hi = fmaxf(m16[i], m16[i | d]);
          m16[i] = lo; m16[i | d] = hi;
        }
      }
    }
    if (!(s & 1)) {                          // lanes 0..31 of each wave
#pragma unroll
      for (int i = 0; i < 16; ++i) slist[(w * 16 + i) * 32 + p] = m16[i];
    }
  }
  __syncthreads();
  // Phase 2: merge tree 8 -> 4 -> 2 -> 1 lists (parallel over points)
  for (int W = 4; W >= 1; W >>= 1) {
    int u = tid >> 5;
    bool act = (u < W);
    float a[16], bb[16];
    if (act) {
#pragma unroll
      for (int i = 0; i < 16; ++i) a[i]  = slist[((2 * u) * 16 + i) * 32 + p];
#pragma unroll
      for (int i = 0; i < 16; ++i) bb[i] = slist[((2 * u + 1) * 16 + i) * 32 + p];
    }
    __syncthreads();
    if (act) {
      float m16[16];
#pragma unroll
      for (int i = 0; i < 16; ++i) m16[i] = fminf(a[i], bb[15 - i]);
#pragma unroll
      for (int d = 8; d >= 1; d >>= 1) {
#pragma unroll
        for (int i = 0; i < 16; ++i) {
          if (!(i & d)) {
            float lo = fminf(m16[i], m16[i | d]);
            float hi = fmaxf(m16[i], m16[i | d]);
            m16[i] = lo; m16[i | d] = hi;
          }
        }
      }
#pragma unroll
      for (int i = 0; i < 16; ++i) slist[(u * 16 + i) * 32 + p] = m16[i];
    }
    __syncthreads();
  }
  float tau = slist[15 * 32 + p];            // exact 16th smallest (self excluded)
  __syncthreads();                           // everyone has tau; reuse slist region
  for (int j = tid; j < 32 * 20; j += THREADS) sidx[j] = 0;
  if (tid < 32) scnt[tid] = 0;
  __syncthreads();
  // Phase 3: rescan, collect indices with d2 <= tau (same dist2f -> bit-exact)
  if (w == wself) {
#pragma unroll 4
    for (int c = 0; c < 128; ++c) {
      float4 q = Cs[c];
      float d2 = dist2f(mex, mey, mez, sqn, q);
      int j = s * 128 + c;
      if (d2 <= tau && j != n) {
        int pos = atomicAdd(&scnt[p], 1);
        if (pos < 20) { sd2[p * 20 + pos] = d2; sidx[p * 20 + pos] = j; }
      }
    }
  } else {
#pragma unroll 4
    for (int c = 0; c < 128; ++c) {
      float4 q = Cs[c];
      float d2 = dist2f(mex, mey, mez, sqn, q);
      int j = s * 128 + c;
      if (d2 <= tau) {
        int pos = atomicAdd(&scnt[p], 1);
        if (pos < 20) { sd2[p * 20 + pos] = d2; sidx[p * 20 + pos] = j; }
      }
    }
  }
  __syncthreads();
  // Phase 4: rare tie fixup — keep 16 smallest by (d2, idx) lexicographic
  if (tid < 32) {
    int c = scnt[tid]; if (c > 20) c = 20;
    if (c > 16) {
      for (int t = 0; t < 16; ++t) {
        int best = t;
        for (int u = t + 1; u < c; ++u) {
          float da = sd2[tid * 20 + u], db = sd2[tid * 20 + best];
          int ia = sidx[tid * 20 + u], ib = sidx[tid * 20 + best];
          if (da < db || (da == db && ia < ib)) best = u;
        }
        float td = sd2[tid * 20 + t]; sd2[tid * 20 + t] = sd2[tid * 20 + best]; sd2[tid * 20 + best] = td;
        int ti = sidx[tid * 20 + t]; sidx[tid * 20 + t] = sidx[tid * 20 + best]; sidx[tid * 20 + best] = ti;
      }
    }
  }
  __syncthreads();
  {
    int pp = tid >> 4, kk = tid & 15;        // 512 threads = 32 pts x 16 nbrs
    knn_out[((size_t)b * NPTS + chunk * CHUNK_PTS + pp) * KNB + kk] = sidx[pp * 20 + kk];
  }
}

// Fused edge-MLP + max. 16 lanes/point; neighbor-dependent 12x12 blocks only.
__global__ __launch_bounds__(256) void mlp_kernel(
    const float* __restrict__ pre, const float* __restrict__ aux,
    const int* __restrict__ knn, const float* __restrict__ x,
    const float* __restrict__ w2, const float* __restrict__ g2,
    const float* __restrict__ v2, const float* __restrict__ w3,
    float* __restrict__ out) {
  __shared__ float sW2h[144], sW3h2[144], sW3h1[144];
  __shared__ float sout[87 * 16];
  int tid = threadIdx.x;
  if (tid < 144) {
    int o = tid / 12, i = tid - o * 12;
    float inv2 = g2[o] / sqrtf(v2[o] + EPS);
    sW2h[tid]  = w2[o * 60 + i] * inv2;
    sW3h2[tid] = w3[o * 72 + i];
    sW3h1[tid] = w3[o * 72 + 12 + i];
  }
  __syncthreads();
  int k = tid & 15, pl = tid >> 4;
  int p = blockIdx.x * 16 + pl;            // 0..16383
  int b = p >> 11, n = p & (NPTS - 1);
  int nb = knn[(size_t)p * KNB + k];
  const float4* u4 = (const float4*)(aux + (size_t)p * 72);
  const float4* a4 = (const float4*)(aux + ((size_t)(b << 11) + nb) * 72 + 36);
  float uc[36], av[36];
#pragma unroll
  for (int i = 0; i < 9; ++i) {
    float4 t = u4[i];
    uc[4*i] = t.x; uc[4*i+1] = t.y; uc[4*i+2] = t.z; uc[4*i+3] = t.w;
    float4 t2 = a4[i];
    av[4*i] = t2.x; av[4*i+1] = t2.y; av[4*i+2] = t2.z; av[4*i+3] = t2.w;
  }
  float h1[12], h2[12], h3[12];
#pragma unroll
  for (int o = 0; o < 12; ++o) h1[o] = fmaxf(uc[o] + av[o], 0.f);
#pragma unroll
  for (int o = 0; o < 12; ++o) {
    float a = uc[12 + o] + av[12 + o];
#pragma unroll
    for (int i = 0; i < 12; ++i) a = fmaf(sW2h[o * 12 + i], h1[i], a);
    h2[o] = fmaxf(a, 0.f);
  }
#pragma unroll
  for (int o = 0; o < 12; ++o) {
    float a = uc[24 + o] + av[24 + o];
#pragma unroll
    for (int i = 0; i < 12; ++i) a = fmaf(sW3h2[o * 12 + i], h2[i], a);
#pragma unroll
    for (int i = 0; i < 12; ++i) a = fmaf(sW3h1[o * 12 + i], h1[i], a);
    h3[o] = a;
  }
  float nbf[24];
  const float4* pn4 = (const float4*)(pre + ((size_t)(b << 11) + nb) * 24);
#pragma unroll
  for (int i = 0; i < 6; ++i) {
    float4 t = pn4[i];
    nbf[4*i] = t.x; nbf[4*i+1] = t.y; nbf[4*i+2] = t.z; nbf[4*i+3] = t.w;
  }
#pragma unroll
  for (int m = 1; m < 16; m <<= 1) {
#pragma unroll
    for (int o = 0; o < 12; ++o) {
      h1[o] = fmaxf(h1[o], __shfl_xor(h1[o], m, 16));
      h2[o] = fmaxf(h2[o], __shfl_xor(h2[o], m, 16));
      h3[o] = fmaxf(h3[o], __shfl_xor(h3[o], m, 16));
    }
#pragma unroll
    for (int i = 0; i < 24; ++i)
      nbf[i] = fmaxf(nbf[i], __shfl_xor(nbf[i], m, 16));
  }
  if (k == 0) {
    const float4* c4 = (const float4*)(pre + (size_t)p * 24);
#pragma unroll
    for (int o = 0; o < 12; ++o) {
      sout[(0  + o) * 16 + pl] = h3[o];
      sout[(12 + o) * 16 + pl] = h2[o];
      sout[(24 + o) * 16 + pl] = h1[o];
    }
#pragma unroll
    for (int i = 0; i < 6; ++i) {
      float4 t = c4[i];
      sout[(36 + 4*i    ) * 16 + pl] = t.x;
      sout[(36 + 4*i + 1) * 16 + pl] = t.y;
      sout[(36 + 4*i + 2) * 16 + pl] = t.z;
      sout[(36 + 4*i + 3) * 16 + pl] = t.w;
    }
#pragma unroll
    for (int i = 0; i < 24; ++i) sout[(60 + i) * 16 + pl] = nbf[i];
    const float* xb = x + (size_t)b * 3 * NPTS + n;
    sout[84 * 16 + pl] = xb[0];
    sout[85 * 16 + pl] = xb[NPTS];
    sout[86 * 16 + pl] = xb[2 * NPTS];
  }
  __syncthreads();
  int n0 = (blockIdx.x * 16) & (NPTS - 1);
  float* ob = out + (size_t)b * 87 * NPTS;
  for (int j2 = tid; j2 < 87 * 16; j2 += 256) {
    int c = j2 >> 4, i = j2 & 15;
    ob[(size_t)c * NPTS + n0 + i] = sout[j2];
  }
}

extern "C" void kernel_launch(void* const* d_in, const int* in_sizes, int n_in,
                              void* d_out, int out_size, void* d_ws, size_t ws_size,
                              hipStream_t stream) {
  (void)in_sizes; (void)n_in; (void)out_size; (void)ws_size;
  const float* x     = (const float*)d_in[0];
  const float* w_pre = (const float*)d_in[1];
  const float* b_pre = (const float*)d_in[2];
  const float* g_pre = (const float*)d_in[3];
  const float* be_pre= (const float*)d_in[4];
  const float* m_pre = (const float*)d_in[5];
  const float* v_pre = (const float*)d_in[6];
  const float* w1    = (const float*)d_in[7];
  const float* g1    = (const float*)d_in[8];
  const float* be1   = (const float*)d_in[9];
  const float* m1    = (const float*)d_in[10];
  const float* v1    = (const float*)d_in[11];
  const float* w2    = (const float*)d_in[12];
  const float* g2    = (const float*)d_in[13];
  const float* be2   = (const float*)d_in[14];
  const float* m2    = (const float*)d_in[15];
  const float* v2    = (const float*)d_in[16];
  const float* w3    = (const float*)d_in[17];
  float* ws  = (float*)d_ws;
  float* pre = ws + WS_PRE;
  float* aux = ws + WS_AUX;
  int*   knn = (int*)(ws + WS_IDX);
  float* out = (float*)d_out;

  fused_kernel<<<KNN_BLKS, THREADS, FUSED_LDS, stream>>>(
      x, w_pre, b_pre, g_pre, be_pre, m_pre, v_pre,
      w1, g1, be1, m1, v1, w2, g2, be2, m2, v2, w3,
      pre, aux, knn);
  mlp_kernel<<<NBATCH * NPTS / 16, 256, 0, stream>>>(pre, aux, knn, x,
                                                     w2, g2, v2, w3, out);
}